// Round 4
// baseline (121.998 us; speedup 1.0000x reference)
//
#include <hip/hip_runtime.h>
#include <math.h>

#define IMG_H 256
#define IMG_W 256
#define EPSV 1e-4f
#define SEGS 8            // depth segments per pixel (1 wave each)
#define PIX_PER_BLK 64    // pixels per strip (= wave width); one row-strip
#define SKIP_EPS 1e-7f    // alpha below this may be skipped (err <= N*eps)
#define MAXN 2048         // LDS depth buffer capacity (problem: N=512)
#define LOG2E 1.442695041f
#define GRID_BLOCKS 256   // <= total residency capacity -> all blocks resident
#define FLAG_MAGIC 0x1B7E2C9Du   // 4 distinct bytes: no repeated-byte poison collision
#define FLAG_OFFSET (1u << 20)   // flag word 1 MiB into workspace (gbuf uses 24 KB)

#if __has_builtin(__builtin_amdgcn_exp2f)
#define EXP2F(x) __builtin_amdgcn_exp2f(x)
#else
#define EXP2F(x) __expf((x) * 0.6931471805599453f)
#endif

// 48-byte per-gaussian record, depth-sorted. Three float4s:
//  h0 = {mx, my, rx2, ry2}   cull data: skip if dxmin^2>rx2 || dy^2>ry2
//  h1 = {qa, qb, qc, coeff}  q = qa*dx^2 + qb*dx*dy + qc*dy^2 (= -0.5*mahal)
//  h2 = {cr, cg, cb, pad}    alpha = coeff*exp(q)
struct __align__(16) GData {
    float4 h0, h1, h2;
};

__device__ __forceinline__ float rlane(float v, int n) {
    return __int_as_float(__builtin_amdgcn_readlane(__float_as_int(v), n));
}

// ONE regular (graph-capturable) kernel, grid = 256 x 512, lb(512,2).
// Residency: 8 waves/block = 2/EU, ~12 KB LDS, VGPR<=256 -> every CU can
// host >=1 block, capacity (>=256) >= grid, so ALL blocks are resident
// immediately under any dispatch order; the spin-wait below cannot deadlock.
//
// Block 0: full preprocess (depth rank via per-thread broadcast scan of the
// LDS depth array -- all lanes read the SAME address sequence, conflict-free
// broadcast), GData scatter-write to gbuf at sorted rank, then agent-scope
// release-store of FLAG_MAGIC.  Other blocks: acquire-spin on the flag
// (same fence mechanism cooperative grid.sync used -- proven correct in R3;
// the workspace re-poison resets the flag between timed iterations).
// Then ALL blocks render 4 row-strips each (verified Round-2 arithmetic).
__global__ __launch_bounds__(512, 2)
void GaussianRenderer_fused(const float* __restrict__ means3D,
                            const float* __restrict__ covs3d,
                            const float* __restrict__ colors,
                            const float* __restrict__ opac,
                            const float* __restrict__ Km,
                            const float* __restrict__ Rm,
                            const float* __restrict__ tv,
                            GData* __restrict__ gbuf,
                            unsigned* __restrict__ flag,
                            float* __restrict__ out, int N)
{
    __shared__ __align__(16) float sdepth[MAXN + 4];
    __shared__ float4 part[SEGS][PIX_PER_BLK];

    const int Npad = (N + 3) & ~3;

    if (blockIdx.x == 0) {
        // ================= preprocess (single block) =================
        const float R00=Rm[0], R01=Rm[1], R02=Rm[2];
        const float R10=Rm[3], R11=Rm[4], R12=Rm[5];
        const float R20=Rm[6], R21=Rm[7], R22=Rm[8];
        const float t0=tv[0], t1=tv[1], t2=tv[2];

        // ---- phase 1: all depths into LDS ----
        for (int i = threadIdx.x; i < Npad; i += 512) {
            float depth = __builtin_inff();           // pad: +inf never counts
            if (i < N) {
                const float m0 = means3D[i*3+0], m1 = means3D[i*3+1], m2 = means3D[i*3+2];
                const float z = R20*m0 + R21*m1 + R22*m2 + t2;
                depth = fmaxf(z, 1.0f);
            }
            sdepth[i] = depth;
        }
        __syncthreads();

        // ---- phase 2+3: rank (broadcast scan) + GData + scatter ----
        for (int g = threadIdx.x; g < N; g += 512) {
            const float depth = sdepth[g];
            int rank = 0;
            {
                const int total4 = Npad >> 2;
                const float4* sd4 = (const float4*)sdepth;
                for (int j4 = 0; j4 < total4; ++j4) {   // same addr all lanes -> broadcast
                    const float4 v = sd4[j4];
                    const int j = j4 * 4;
                    rank += (v.x < depth || (v.x == depth && (j + 0) < g)) ? 1 : 0;
                    rank += (v.y < depth || (v.y == depth && (j + 1) < g)) ? 1 : 0;
                    rank += (v.z < depth || (v.z == depth && (j + 2) < g)) ? 1 : 0;
                    rank += (v.w < depth || (v.w == depth && (j + 3) < g)) ? 1 : 0;
                }
            }

            const float K00=Km[0], K01=Km[1], K02=Km[2];
            const float K10=Km[3], K11=Km[4], K12=Km[5];
            const float K20=Km[6], K21=Km[7], K22=Km[8];
            const float fx=Km[0], fy=Km[4];

            const float m0 = means3D[g*3+0], m1 = means3D[g*3+1], m2 = means3D[g*3+2];
            const float c0 = R00*m0 + R01*m1 + R02*m2 + t0;
            const float c1 = R10*m0 + R11*m1 + R12*m2 + t1;
            const float c2 = R20*m0 + R21*m1 + R22*m2 + t2;
            const float z = c2;
            const float depthc = fmaxf(z, 1.0f);

            const float s0 = K00*c0 + K01*c1 + K02*c2;
            const float s1 = K10*c0 + K11*c1 + K12*c2;
            const float s2 = K20*c0 + K21*c1 + K22*c2;
            const float mx = s0 / s2, my = s1 / s2;

            // Sigma_cam = R * C * R^T (top-left 2x2)
            const float* C = covs3d + g*9;
            const float C00=C[0],C01=C[1],C02=C[2],C10=C[3],C11=C[4],C12=C[5],C20=C[6],C21=C[7],C22=C[8];
            const float M00 = R00*C00 + R01*C10 + R02*C20;
            const float M01 = R00*C01 + R01*C11 + R02*C21;
            const float M02 = R00*C02 + R01*C12 + R02*C22;
            const float M10 = R10*C00 + R11*C10 + R12*C20;
            const float M11 = R10*C01 + R11*C11 + R12*C21;
            const float M12 = R10*C02 + R11*C12 + R12*C22;
            const float S00 = M00*R00 + M01*R01 + M02*R02;
            const float S01 = M00*R10 + M01*R11 + M02*R12;
            const float S10 = M10*R00 + M11*R01 + M12*R02;
            const float S11 = M10*R10 + M11*R11 + M12*R12;

            // Reference einsum is J^T Sigma J cropped to [:2,:2]
            const float j0 = fx / z, j1 = fy / z;
            const float a  = j0*j0*S00 + EPSV;
            const float b  = j0*S01*j1;
            const float cc = j1*S10*j0;
            const float d  = j1*j1*S11 + EPSV;

            const float det    = a*d - b*cc;
            const float invdet = 1.0f / det;
            const float norm   = 0.15915494309189535f / sqrtf(det);
            const bool valid   = (depthc > 1.0f) && (depthc < 50.0f);
            const float coeff  = valid ? (opac[g] * norm) : 0.0f;

            // Conservative cull radii via Schur bound
            float rx2 = -1.0f, ry2 = -1.0f;       // -1 => always cull
            if (coeff > SKIP_EPS) {
                const float L = __logf(coeff * (1.0f / SKIP_EPS));
                rx2 = 2.0f * a * L;
                ry2 = 2.0f * d * L;
            }

            GData gd;
            gd.h0 = make_float4(mx, my, rx2, ry2);
            gd.h1 = make_float4(-0.5f * d * invdet,
                                 0.5f * (b + cc) * invdet,
                                -0.5f * a * invdet,
                                coeff);
            gd.h2 = make_float4(colors[g*3+0], colors[g*3+1], colors[g*3+2], 0.f);
            gbuf[rank] = gd;
        }
        __syncthreads();            // all gbuf stores issued & drained (vmcnt)
        __threadfence();            // agent-scope fence: publish gbuf
        if (threadIdx.x == 0)
            __hip_atomic_store(flag, FLAG_MAGIC, __ATOMIC_RELEASE,
                               __HIP_MEMORY_SCOPE_AGENT);
    } else {
        // ================= wait for producer =================
        if (threadIdx.x == 0) {
            while (__hip_atomic_load(flag, __ATOMIC_ACQUIRE,
                                     __HIP_MEMORY_SCOPE_AGENT) != FLAG_MAGIC)
                __builtin_amdgcn_s_sleep(2);
        }
        __syncthreads();
    }

    // ================= render: 4 strips per block =================
    const int seg  = __builtin_amdgcn_readfirstlane(threadIdx.x >> 6);
    const int lane = threadIdx.x & 63;
    const int segLen = (N + SEGS - 1) / SEGS;
    const int gBeg = seg * segLen;
    const int gEnd = (gBeg + segLen < N) ? (gBeg + segLen) : N;
    const int nStrips = (IMG_H * IMG_W) / PIX_PER_BLK;

    for (int strip = blockIdx.x; strip < nStrips; strip += GRID_BLOCKS) {
        const int p    = strip * PIX_PER_BLK + lane;
        const float px = (float)(p & (IMG_W - 1));
        const float py = (float)(p >> 8);                   // uniform per strip
        const float cx = (float)((strip * PIX_PER_BLK) & (IMG_W - 1)) + 31.5f;

        float T = 1.0f, ar = 0.0f, ag = 0.0f, ab = 0.0f;

        for (int base = gBeg; base < gEnd; base += 64) {
            const int idx = base + lane;
            float4 h0 = make_float4(0.f, 0.f, -1.f, -1.f);
            float4 h1 = make_float4(0.f, 0.f, 0.f, 0.f);  // co=0 -> lc2=-inf -> alpha=0
            float4 h2 = make_float4(0.f, 0.f, 0.f, 0.f);
            if (idx < gEnd) {
                const GData gd = gbuf[idx];   // 3x global_load_dwordx4, L2-resident
                h0 = gd.h0; h1 = gd.h1; h2 = gd.h2;
            }
            // Row specialization (py uniform), additive in base-2 exponent
            // domain (multiplicative split NaN'd: 0*inf when partial
            // exponents are +-1000s with a moderate sum).
            const float dy  = py - h0.y;
            const float qa2 = h1.x * LOG2E;
            const float qb2 = (h1.y * dy) * LOG2E;
            const float lc2 = __logf(h1.w) * LOG2E + ((h1.z * dy) * dy) * LOG2E;

            // Strip cull: row py, columns [cx-31.5, cx+31.5].
            const float dxm = fmaxf(fabsf(h0.x - cx) - 31.5f, 0.0f);
            const bool hit = (dxm * dxm <= h0.z) && (dy * dy <= h0.w);

            unsigned long long m = __ballot(hit);
            while (m) {
                const int n = __builtin_ctzll(m);
                m &= m - 1;
                const float mx = rlane(h0.x, n);
                const float qa = rlane(qa2,  n);
                const float qb = rlane(qb2,  n);
                const float lc = rlane(lc2,  n);
                const float cr = rlane(h2.x, n);
                const float cg = rlane(h2.y, n);
                const float cb = rlane(h2.z, n);

                const float dx = px - mx;
                const float alpha = EXP2F((qa*dx + qb)*dx + lc);
                const float w = alpha * T;
                ar += w * cr;
                ag += w * cg;
                ab += w * cb;
                T  -= w;                     // T *= (1 - alpha)
            }
        }

        __syncthreads();      // previous strip's combine reads of part[] done
        part[seg][lane] = make_float4(ar, ag, ab, T);
        __syncthreads();

        if (seg == 0) {
            float Tp = 1.0f, r = 0.0f, gg = 0.0f, b = 0.0f;
            #pragma unroll
            for (int s = 0; s < SEGS; ++s) {
                const float4 v = part[s][lane];
                r  += Tp * v.x;
                gg += Tp * v.y;
                b  += Tp * v.z;
                Tp *= v.w;
            }
            out[p*3 + 0] = r;
            out[p*3 + 1] = gg;
            out[p*3 + 2] = b;
        }
    }
}

extern "C" void kernel_launch(void* const* d_in, const int* in_sizes, int n_in,
                              void* d_out, int out_size, void* d_ws, size_t ws_size,
                              hipStream_t stream)
{
    const float* means3D = (const float*)d_in[0];
    const float* covs3d  = (const float*)d_in[1];
    const float* colors  = (const float*)d_in[2];
    const float* opac    = (const float*)d_in[3];
    const float* Km      = (const float*)d_in[4];
    const float* Rm      = (const float*)d_in[5];
    const float* tv      = (const float*)d_in[6];
    const int N = in_sizes[3];  // opacities: (N,)

    GData* gbuf    = (GData*)d_ws;
    unsigned* flag = (unsigned*)((char*)d_ws + FLAG_OFFSET);

    GaussianRenderer_fused<<<GRID_BLOCKS, 512, 0, stream>>>(
        means3D, covs3d, colors, opac, Km, Rm, tv, gbuf, flag,
        (float*)d_out, N);
}

// Round 5
// 87.574 us; speedup vs baseline: 1.3931x; 1.3931x over previous
//
#include <hip/hip_runtime.h>
#include <math.h>

#define IMG_H 256
#define IMG_W 256
#define EPSV 1e-4f
#define SEGS 8            // depth segments per pixel (1 wave each)
#define PIX_PER_BLK 64    // pixels per strip (= wave width); one row-strip
#define SKIP_EPS 1e-7f    // alpha below this may be skipped (err <= N*eps)
#define MAXN_LDS 1024     // LDS capacity for sorted gaussians (problem: N=512)
#define LOG2E 1.442695041f
#define GRID_BLOCKS 256   // ~1 block/CU; blocks fully independent (no sync!)

#if __has_builtin(__builtin_amdgcn_exp2f)
#define EXP2F(x) __builtin_amdgcn_exp2f(x)
#else
#define EXP2F(x) __expf((x) * 0.6931471805599453f)
#endif

__device__ __forceinline__ float rlane(float v, int n) {
    return __int_as_float(__builtin_amdgcn_readlane(__float_as_int(v), n));
}

// ONE regular kernel, grid = 256 x 512, NO workspace, NO cross-block
// dependency (R3/R4 lesson: any grid-wide sync -- cooperative or DIY spin --
// costs 38-48us at 256 blocks; the dependency must be eliminated instead).
//
// Each block independently (redundantly -- it's cheap and parallel):
//  A) 512 threads: depth of gaussian tid -> LDS sdepth (pad +inf)
//  B) rank via broadcast scan: each thread compares its depth against all
//     Npad depths, read as float4 with ALL LANES AT THE SAME ADDRESS
//     (LDS broadcast, conflict-free). ~8 waves x 128 ds_read_b128 per block.
//  C) full GData for gaussian tid, scatter-write into LDS arrays at its
//     sorted rank (sh0/sh1/sh2).
//  barrier
//  D) render 4 row-strips (strip = blockIdx.x + 256k): 8 waves = 8 depth
//     segments; params come from LDS; per-hit math in additive base-2
//     exponent domain (R2-verified): alpha = exp2((qa2*dx+qb2)*dx + lc2).
__global__ __launch_bounds__(512, 2)
void GaussianRenderer_all(const float* __restrict__ means3D,
                          const float* __restrict__ covs3d,
                          const float* __restrict__ colors,
                          const float* __restrict__ opac,
                          const float* __restrict__ Km,
                          const float* __restrict__ Rm,
                          const float* __restrict__ tv,
                          float* __restrict__ out, int N)
{
    __shared__ __align__(16) float sdepth[MAXN_LDS + 4];
    __shared__ float4 sh0[MAXN_LDS];
    __shared__ float4 sh1[MAXN_LDS];
    __shared__ float4 sh2[MAXN_LDS];
    __shared__ float4 part[SEGS][PIX_PER_BLK];

    const float R00=Rm[0], R01=Rm[1], R02=Rm[2];
    const float R10=Rm[3], R11=Rm[4], R12=Rm[5];
    const float R20=Rm[6], R21=Rm[7], R22=Rm[8];
    const float t0=tv[0], t1=tv[1], t2=tv[2];

    const int Npad = (N + 3) & ~3;          // N=512 fixed; fits MAXN_LDS

    // ---- A: all depths into LDS ----
    for (int i = threadIdx.x; i < Npad; i += 512) {
        float depth = __builtin_inff();     // pad: +inf never counts in ranks
        if (i < N) {
            const float m0 = means3D[i*3+0], m1 = means3D[i*3+1], m2 = means3D[i*3+2];
            const float z = R20*m0 + R21*m1 + R22*m2 + t2;
            depth = fmaxf(z, 1.0f);
        }
        sdepth[i] = depth;
    }
    __syncthreads();

    // ---- B+C: rank (broadcast scan) + GData + LDS scatter ----
    for (int g = threadIdx.x; g < N; g += 512) {
        const float depth = sdepth[g];
        int rank = 0;
        {
            const int total4 = Npad >> 2;
            const float4* sd4 = (const float4*)sdepth;
            for (int j4 = 0; j4 < total4; ++j4) {   // same addr all lanes -> broadcast
                const float4 v = sd4[j4];
                const int j = j4 * 4;
                rank += (v.x < depth || (v.x == depth && (j + 0) < g)) ? 1 : 0;
                rank += (v.y < depth || (v.y == depth && (j + 1) < g)) ? 1 : 0;
                rank += (v.z < depth || (v.z == depth && (j + 2) < g)) ? 1 : 0;
                rank += (v.w < depth || (v.w == depth && (j + 3) < g)) ? 1 : 0;
            }
        }

        const float K00=Km[0], K01=Km[1], K02=Km[2];
        const float K10=Km[3], K11=Km[4], K12=Km[5];
        const float K20=Km[6], K21=Km[7], K22=Km[8];
        const float fx=Km[0], fy=Km[4];

        const float m0 = means3D[g*3+0], m1 = means3D[g*3+1], m2 = means3D[g*3+2];
        const float c0 = R00*m0 + R01*m1 + R02*m2 + t0;
        const float c1 = R10*m0 + R11*m1 + R12*m2 + t1;
        const float c2 = R20*m0 + R21*m1 + R22*m2 + t2;
        const float z = c2;
        const float depthc = fmaxf(z, 1.0f);

        const float s0 = K00*c0 + K01*c1 + K02*c2;
        const float s1 = K10*c0 + K11*c1 + K12*c2;
        const float s2 = K20*c0 + K21*c1 + K22*c2;
        const float mx = s0 / s2, my = s1 / s2;

        // Sigma_cam = R * C * R^T (top-left 2x2)
        const float* C = covs3d + g*9;
        const float C00=C[0],C01=C[1],C02=C[2],C10=C[3],C11=C[4],C12=C[5],C20=C[6],C21=C[7],C22=C[8];
        const float M00 = R00*C00 + R01*C10 + R02*C20;
        const float M01 = R00*C01 + R01*C11 + R02*C21;
        const float M02 = R00*C02 + R01*C12 + R02*C22;
        const float M10 = R10*C00 + R11*C10 + R12*C20;
        const float M11 = R10*C01 + R11*C11 + R12*C21;
        const float M12 = R10*C02 + R11*C12 + R12*C22;
        const float S00 = M00*R00 + M01*R01 + M02*R02;
        const float S01 = M00*R10 + M01*R11 + M02*R12;
        const float S10 = M10*R00 + M11*R01 + M12*R02;
        const float S11 = M10*R10 + M11*R11 + M12*R12;

        // Reference einsum is J^T Sigma J cropped to [:2,:2]
        const float j0 = fx / z, j1 = fy / z;
        const float a  = j0*j0*S00 + EPSV;
        const float b  = j0*S01*j1;
        const float cc = j1*S10*j0;
        const float d  = j1*j1*S11 + EPSV;

        const float det    = a*d - b*cc;
        const float invdet = 1.0f / det;
        const float norm   = 0.15915494309189535f / sqrtf(det);
        const bool valid   = (depthc > 1.0f) && (depthc < 50.0f);
        const float coeff  = valid ? (opac[g] * norm) : 0.0f;

        // Conservative cull radii via Schur bound
        float rx2 = -1.0f, ry2 = -1.0f;       // -1 => always cull
        if (coeff > SKIP_EPS) {
            const float L = __logf(coeff * (1.0f / SKIP_EPS));
            rx2 = 2.0f * a * L;
            ry2 = 2.0f * d * L;
        }

        sh0[rank] = make_float4(mx, my, rx2, ry2);
        sh1[rank] = make_float4(-0.5f * d * invdet,
                                 0.5f * (b + cc) * invdet,
                                -0.5f * a * invdet,
                                coeff);
        sh2[rank] = make_float4(colors[g*3+0], colors[g*3+1], colors[g*3+2], 0.f);
    }
    __syncthreads();

    // ---- D: render 4 strips per block ----
    const int seg  = __builtin_amdgcn_readfirstlane(threadIdx.x >> 6);
    const int lane = threadIdx.x & 63;
    const int segLen = (N + SEGS - 1) / SEGS;
    const int gBeg = seg * segLen;
    const int gEnd = (gBeg + segLen < N) ? (gBeg + segLen) : N;
    const int nStrips = (IMG_H * IMG_W) / PIX_PER_BLK;

    for (int strip = blockIdx.x; strip < nStrips; strip += GRID_BLOCKS) {
        const int p    = strip * PIX_PER_BLK + lane;
        const float px = (float)(p & (IMG_W - 1));
        const float py = (float)(p >> 8);                   // uniform per strip
        const float cx = (float)((strip * PIX_PER_BLK) & (IMG_W - 1)) + 31.5f;

        float T = 1.0f, ar = 0.0f, ag = 0.0f, ab = 0.0f;

        for (int base = gBeg; base < gEnd; base += 64) {
            const int idx = base + lane;
            float4 h0 = make_float4(0.f, 0.f, -1.f, -1.f);
            float4 h1 = make_float4(0.f, 0.f, 0.f, 0.f);  // co=0 -> lc2=-inf -> alpha=0
            float4 h2 = make_float4(0.f, 0.f, 0.f, 0.f);
            if (idx < gEnd) {
                h0 = sh0[idx];          // ds_read_b128 x3, stride 16B
                h1 = sh1[idx];
                h2 = sh2[idx];
            }
            // Row specialization (py uniform), additive in base-2 exponent
            // domain (multiplicative split NaN'd in R1: 0*inf when partial
            // exponents are +-1000s with a moderate sum).
            const float dy  = py - h0.y;
            const float qa2 = h1.x * LOG2E;
            const float qb2 = (h1.y * dy) * LOG2E;
            const float lc2 = __logf(h1.w) * LOG2E + ((h1.z * dy) * dy) * LOG2E;

            // Strip cull: row py, columns [cx-31.5, cx+31.5].
            const float dxm = fmaxf(fabsf(h0.x - cx) - 31.5f, 0.0f);
            const bool hit = (dxm * dxm <= h0.z) && (dy * dy <= h0.w);

            unsigned long long m = __ballot(hit);
            while (m) {
                const int n = __builtin_ctzll(m);
                m &= m - 1;
                const float mx = rlane(h0.x, n);
                const float qa = rlane(qa2,  n);
                const float qb = rlane(qb2,  n);
                const float lc = rlane(lc2,  n);
                const float cr = rlane(h2.x, n);
                const float cg = rlane(h2.y, n);
                const float cb = rlane(h2.z, n);

                const float dx = px - mx;
                const float alpha = EXP2F((qa*dx + qb)*dx + lc);
                const float w = alpha * T;
                ar += w * cr;
                ag += w * cg;
                ab += w * cb;
                T  -= w;                     // T *= (1 - alpha)
            }
        }

        __syncthreads();      // previous strip's combine reads of part[] done
        part[seg][lane] = make_float4(ar, ag, ab, T);
        __syncthreads();

        if (seg == 0) {
            float Tp = 1.0f, r = 0.0f, gg = 0.0f, b = 0.0f;
            #pragma unroll
            for (int s = 0; s < SEGS; ++s) {
                const float4 v = part[s][lane];
                r  += Tp * v.x;
                gg += Tp * v.y;
                b  += Tp * v.z;
                Tp *= v.w;
            }
            out[p*3 + 0] = r;
            out[p*3 + 1] = gg;
            out[p*3 + 2] = b;
        }
    }
}

extern "C" void kernel_launch(void* const* d_in, const int* in_sizes, int n_in,
                              void* d_out, int out_size, void* d_ws, size_t ws_size,
                              hipStream_t stream)
{
    const float* means3D = (const float*)d_in[0];
    const float* covs3d  = (const float*)d_in[1];
    const float* colors  = (const float*)d_in[2];
    const float* opac    = (const float*)d_in[3];
    const float* Km      = (const float*)d_in[4];
    const float* Rm      = (const float*)d_in[5];
    const float* tv      = (const float*)d_in[6];
    const int N = in_sizes[3];  // opacities: (N,)

    (void)d_ws; (void)ws_size;  // workspace unused: no cross-kernel handoff

    GaussianRenderer_all<<<GRID_BLOCKS, 512, 0, stream>>>(
        means3D, covs3d, colors, opac, Km, Rm, tv, (float*)d_out, N);
}

// Round 6
// 73.654 us; speedup vs baseline: 1.6564x; 1.1890x over previous
//
#include <hip/hip_runtime.h>
#include <math.h>

#define IMG_H 256
#define IMG_W 256
#define EPSV 1e-4f
#define SEGS 8            // depth segments per pixel (1 wave each)
#define PIX_PER_BLK 64    // pixels per block (= wave width); one row-strip
#define SKIP_EPS 1e-7f    // alpha below this may be skipped (err <= N*eps)
#define GPB 64            // gaussians ranked per preprocess block
#define MAXN 2048         // LDS depth buffer capacity (problem: N=512)
#define LOG2E 1.442695041f

#if __has_builtin(__builtin_amdgcn_exp2f)
#define EXP2F(x) __builtin_amdgcn_exp2f(x)
#else
#define EXP2F(x) __expf((x) * 0.6931471805599453f)
#endif

// 48-byte per-gaussian record, depth-sorted. Three float4s:
//  h0 = {mx, my, rx2, ry2}   cull data: skip if dxmin^2>rx2 || dy^2>ry2
//  h1 = {qa, qb, qc, coeff}  q = qa*dx^2 + qb*dx*dy + qc*dy^2 (= -0.5*mahal)
//  h2 = {cr, cg, cb, pad}    alpha = coeff*exp(q)
struct __align__(16) GData {
    float4 h0, h1, h2;
};

// Grid = ceil(N/64) blocks x 512 threads. Each block:
//  phase 1: all threads compute all N depths into LDS (redundant across
//           blocks -- trivial VALU, removes cross-block dependency)
//  phase 2: 8 threads per gaussian compute partial ranks (global O(N^2)
//           spread over 8 CUs instead of 1 -> LDS-BW floor /8)
//  phase 3: 64 threads compute full GData for this block's gaussians and
//           scatter-write to the depth-sorted position.
//
// Session journal (R3/R4/R5): do NOT fuse these two kernels. Cooperative
// grid.sync = +38us; DIY spin barrier = +48us (single-line coherence
// serialization at 256 blocks); per-block redundant preprocess = +14us
// (the O(N^2) rank scan + LDS broadcast reads paid on every CU). The
// kernel boundary is cheaper than any grid-wide alternative measured.
__global__ __launch_bounds__(512)
void GaussianRenderer_preprocess(const float* __restrict__ means3D,
                                 const float* __restrict__ covs3d,
                                 const float* __restrict__ colors,
                                 const float* __restrict__ opac,
                                 const float* __restrict__ Km,
                                 const float* __restrict__ Rm,
                                 const float* __restrict__ tv,
                                 GData* __restrict__ out, int N)
{
    __shared__ __align__(16) float sdepth[MAXN + 4];
    __shared__ int srank[512];

    const float R00=Rm[0], R01=Rm[1], R02=Rm[2];
    const float R10=Rm[3], R11=Rm[4], R12=Rm[5];
    const float R20=Rm[6], R21=Rm[7], R22=Rm[8];
    const float t2=tv[2];

    const int Npad = (N + 3) & ~3;

    // ---- phase 1: depths for ALL gaussians into LDS ----
    for (int i = threadIdx.x; i < Npad; i += 512) {
        float depth = __builtin_inff();           // pad: +inf never counts
        if (i < N) {
            const float m0 = means3D[i*3+0], m1 = means3D[i*3+1], m2 = means3D[i*3+2];
            const float z = R20*m0 + R21*m1 + R22*m2 + t2;
            depth = fmaxf(z, 1.0f);
        }
        sdepth[i] = depth;
    }
    __syncthreads();

    // ---- phase 2: partial ranks, 8 threads per gaussian ----
    {
        const int g   = blockIdx.x * GPB + (threadIdx.x >> 3);
        const int sub = threadIdx.x & 7;
        int rank = 0;
        if (g < N) {
            const float depth = sdepth[g];
            const int total4  = Npad >> 2;
            const int chunk4  = (total4 + 7) >> 3;
            const int b4 = sub * chunk4;
            const int e4 = (b4 + chunk4 < total4) ? (b4 + chunk4) : total4;
            const float4* sd4 = (const float4*)sdepth;
            for (int j4 = b4; j4 < e4; ++j4) {
                const float4 v = sd4[j4];
                const int j = j4 * 4;
                rank += (v.x < depth || (v.x == depth && (j + 0) < g)) ? 1 : 0;
                rank += (v.y < depth || (v.y == depth && (j + 1) < g)) ? 1 : 0;
                rank += (v.z < depth || (v.z == depth && (j + 2) < g)) ? 1 : 0;
                rank += (v.w < depth || (v.w == depth && (j + 3) < g)) ? 1 : 0;
            }
        }
        srank[threadIdx.x] = rank;
    }
    __syncthreads();

    // ---- phase 3: GData + scatter write (64 threads) ----
    const int t = threadIdx.x;
    const int i = blockIdx.x * GPB + t;
    if (t < GPB && i < N) {
        int rank = 0;
        #pragma unroll
        for (int s = 0; s < 8; ++s) rank += srank[t*8 + s];

        const float K00=Km[0], K01=Km[1], K02=Km[2];
        const float K10=Km[3], K11=Km[4], K12=Km[5];
        const float K20=Km[6], K21=Km[7], K22=Km[8];
        const float fx=Km[0], fy=Km[4];
        const float t0=tv[0], t1=tv[1];

        const float m0 = means3D[i*3+0], m1 = means3D[i*3+1], m2 = means3D[i*3+2];
        const float c0 = R00*m0 + R01*m1 + R02*m2 + t0;
        const float c1 = R10*m0 + R11*m1 + R12*m2 + t1;
        const float c2 = R20*m0 + R21*m1 + R22*m2 + t2;
        const float z = c2;
        const float depth = fmaxf(z, 1.0f);

        const float s0 = K00*c0 + K01*c1 + K02*c2;
        const float s1 = K10*c0 + K11*c1 + K12*c2;
        const float s2 = K20*c0 + K21*c1 + K22*c2;
        const float mx = s0 / s2, my = s1 / s2;

        // Sigma_cam = R * C * R^T (top-left 2x2)
        const float* C = covs3d + i*9;
        const float C00=C[0],C01=C[1],C02=C[2],C10=C[3],C11=C[4],C12=C[5],C20=C[6],C21=C[7],C22=C[8];
        const float M00 = R00*C00 + R01*C10 + R02*C20;
        const float M01 = R00*C01 + R01*C11 + R02*C21;
        const float M02 = R00*C02 + R01*C12 + R02*C22;
        const float M10 = R10*C00 + R11*C10 + R12*C20;
        const float M11 = R10*C01 + R11*C11 + R12*C21;
        const float M12 = R10*C02 + R11*C12 + R12*C22;
        const float S00 = M00*R00 + M01*R01 + M02*R02;
        const float S01 = M00*R10 + M01*R11 + M02*R12;
        const float S10 = M10*R00 + M11*R01 + M12*R02;
        const float S11 = M10*R10 + M11*R11 + M12*R12;

        // Reference einsum is J^T Sigma J cropped to [:2,:2] -> only diag fx/z, fy/z enters
        const float j0 = fx / z, j1 = fy / z;
        const float a  = j0*j0*S00 + EPSV;
        const float b  = j0*S01*j1;
        const float cc = j1*S10*j0;
        const float d  = j1*j1*S11 + EPSV;

        const float det    = a*d - b*cc;
        const float invdet = 1.0f / det;
        const float norm   = 0.15915494309189535f / sqrtf(det);  // 1/(2*pi*sqrt(det))
        const bool valid   = (depth > 1.0f) && (depth < 50.0f);
        const float coeff  = valid ? (opac[i] * norm) : 0.0f;

        // Conservative cull radii via Schur bound: alpha < SKIP_EPS guaranteed
        // outside dx^2 > 2*a*ln(coeff/eps) (resp. dy^2, d).
        float rx2 = -1.0f, ry2 = -1.0f;       // -1 => always cull
        if (coeff > SKIP_EPS) {
            const float L = __logf(coeff * (1.0f / SKIP_EPS));
            rx2 = 2.0f * a * L;
            ry2 = 2.0f * d * L;
        }

        GData gd;
        gd.h0 = make_float4(mx, my, rx2, ry2);
        gd.h1 = make_float4(-0.5f * d * invdet,
                             0.5f * (b + cc) * invdet,
                            -0.5f * a * invdet,
                            coeff);
        gd.h2 = make_float4(colors[i*3+0], colors[i*3+1], colors[i*3+2], 0.f);
        out[rank] = gd;
    }
}

__device__ __forceinline__ float rlane(float v, int n) {
    return __int_as_float(__builtin_amdgcn_readlane(__float_as_int(v), n));
}

// Block = 512 threads = 64 pixels x 8 depth-segments (one wave per segment).
// Lane <-> gaussian: each wave loads its 64-gaussian segment coalesced into
// registers.  py is UNIFORM across the wave, so before the hit loop each
// lane folds dy into its own gaussian's coefficients ADDITIVELY in the
// base-2 exponent domain (multiplicative folding NaN'd in R1: exp-split can
// hit 0*inf when the partial exponents are +-1000s with a moderate sum):
//   alpha = exp2( (qa2*dx + qb2)*dx + lc2 )
//   qa2 = qa*log2e, qb2 = qb*dy*log2e, lc2 = log2(co) + qc*dy^2*log2e
// Per-hit broadcast: 7 readlanes, ~8 VALU.
__global__ __launch_bounds__(512)
void GaussianRenderer_render(const GData* __restrict__ g,
                             float* __restrict__ out, int N)
{
    const int seg  = __builtin_amdgcn_readfirstlane(threadIdx.x >> 6);
    const int lane = threadIdx.x & 63;
    const int p    = blockIdx.x * PIX_PER_BLK + lane;
    const float px = (float)(p & (IMG_W - 1));
    const float py = (float)(p >> 8);                       // uniform per block
    const float cx = (float)((blockIdx.x * PIX_PER_BLK) & (IMG_W - 1)) + 31.5f;

    const int segLen = (N + SEGS - 1) / SEGS;
    const int gBeg = seg * segLen;
    const int gEnd = (gBeg + segLen < N) ? (gBeg + segLen) : N;

    float T = 1.0f, ar = 0.0f, ag = 0.0f, ab = 0.0f;

    for (int base = gBeg; base < gEnd; base += 64) {
        const int idx = base + lane;
        float4 h0 = make_float4(0.f, 0.f, -1.f, -1.f);
        float4 h1 = make_float4(0.f, 0.f, 0.f, 0.f);    // co=0 -> lc2=-inf -> alpha=0
        float4 h2 = make_float4(0.f, 0.f, 0.f, 0.f);
        if (idx < gEnd) {
            const GData gd = g[idx];     // coalesced: 3x global_load_dwordx4
            h0 = gd.h0; h1 = gd.h1; h2 = gd.h2;
        }
        // Row specialization (py uniform), additive in base-2 exponent domain.
        const float dy  = py - h0.y;
        const float qa2 = h1.x * LOG2E;
        const float qb2 = (h1.y * dy) * LOG2E;
        // log2(co): co==0 -> -inf; remaining exponent terms are finite, so
        // the sum stays -inf (never NaN) and exp2 -> 0.
        const float lc2 = __logf(h1.w) * LOG2E + ((h1.z * dy) * dy) * LOG2E;

        // Strip cull: this wave covers row py, columns [cx-31.5, cx+31.5].
        const float dxm = fmaxf(fabsf(h0.x - cx) - 31.5f, 0.0f);
        const bool hit = (dxm * dxm <= h0.z) && (dy * dy <= h0.w);

        unsigned long long m = __ballot(hit);
        while (m) {
            const int n = __builtin_ctzll(m);
            m &= m - 1;
            const float mx = rlane(h0.x, n);
            const float qa = rlane(qa2,  n);
            const float qb = rlane(qb2,  n);
            const float lc = rlane(lc2,  n);
            const float cr = rlane(h2.x, n);
            const float cg = rlane(h2.y, n);
            const float cb = rlane(h2.z, n);

            const float dx = px - mx;
            const float alpha = EXP2F((qa*dx + qb)*dx + lc);
            const float w = alpha * T;
            ar += w * cr;
            ag += w * cg;
            ab += w * cb;
            T  -= w;                     // T *= (1 - alpha)
        }
    }

    __shared__ float4 part[SEGS][PIX_PER_BLK];
    part[seg][lane] = make_float4(ar, ag, ab, T);
    __syncthreads();

    if (seg == 0) {
        float Tp = 1.0f, r = 0.0f, gg = 0.0f, b = 0.0f;
        #pragma unroll
        for (int s = 0; s < SEGS; ++s) {
            const float4 v = part[s][lane];
            r  += Tp * v.x;
            gg += Tp * v.y;
            b  += Tp * v.z;
            Tp *= v.w;
        }
        out[p*3 + 0] = r;
        out[p*3 + 1] = gg;
        out[p*3 + 2] = b;
    }
}

extern "C" void kernel_launch(void* const* d_in, const int* in_sizes, int n_in,
                              void* d_out, int out_size, void* d_ws, size_t ws_size,
                              hipStream_t stream)
{
    const float* means3D = (const float*)d_in[0];
    const float* covs3d  = (const float*)d_in[1];
    const float* colors  = (const float*)d_in[2];
    const float* opac    = (const float*)d_in[3];
    const float* Km      = (const float*)d_in[4];
    const float* Rm      = (const float*)d_in[5];
    const float* tv      = (const float*)d_in[6];
    const int N = in_sizes[3];  // opacities: (N,)

    GData* gbuf = (GData*)d_ws;

    const int preBlocks = (N + GPB - 1) / GPB;   // 8 for N=512
    GaussianRenderer_preprocess<<<preBlocks, 512, 0, stream>>>(
        means3D, covs3d, colors, opac, Km, Rm, tv, gbuf, N);

    const int total = IMG_H * IMG_W;
    GaussianRenderer_render<<<(total + PIX_PER_BLK - 1) / PIX_PER_BLK, 512, 0, stream>>>(
        gbuf, (float*)d_out, N);
}